// Round 1
// baseline (204.821 us; speedup 1.0000x reference)
//
#include <hip/hip_runtime.h>
#include <hip/hip_bf16.h>

#define B_ 8
#define T_ 2048
#define E_ 1024
#define D_ 128

typedef __attribute__((ext_vector_type(8))) short short8;
typedef __attribute__((ext_vector_type(4))) float floatx4;

__device__ __forceinline__ unsigned short f2b(float f) {
  union { float f; unsigned int u; } v; v.f = f;
  unsigned int u = v.u;
  return (unsigned short)((u + 0x7fffu + ((u >> 16) & 1u)) >> 16);  // RNE
}

#if defined(__has_builtin)
#if __has_builtin(__builtin_amdgcn_exp2f)
#define EXP2F(x) __builtin_amdgcn_exp2f(x)
#else
#define EXP2F(x) exp2f(x)
#endif
#else
#define EXP2F(x) exp2f(x)
#endif

// ---------------------------------------------------------------------------
// Kernel 1: W [1024x128] fp32 -> Wt [128][1024] bf16 (transposed), x3 weights.
// Softmax scale * log2(e) folded into Wq so attn uses exp2 directly.
// ---------------------------------------------------------------------------
__global__ __launch_bounds__(256) void wtrans_kernel(
    const float* __restrict__ Wq, const float* __restrict__ Wk,
    const float* __restrict__ Wv, unsigned short* __restrict__ Wt3) {
  int idx = blockIdx.x * 256 + threadIdx.x;
  if (idx >= 3 * E_ * D_) return;
  int w = idx / (E_ * D_);
  int rem = idx - w * (E_ * D_);
  int k = rem >> 7;
  int n = rem & (D_ - 1);
  const float* W = (w == 0) ? Wq : ((w == 1) ? Wk : Wv);
  float val = W[k * D_ + n];
  if (w == 0) val *= 1.4426950408889634f * 0.08838834764831845f;  // log2e/sqrt(128)
  Wt3[w * (D_ * E_) + n * E_ + k] = f2b(val);
}

// ---------------------------------------------------------------------------
// Kernel 2: QKV projection GEMM. C[16384,128] = X[16384,1024] * W[1024,128].
// 128x128 tile, BK=32, 4 waves each 32 rows (2 m-tiles x 8 n-tiles of 16x16x32).
// blockIdx.y selects weight; y==2 writes V transposed into Vt[b][d][t].
// ---------------------------------------------------------------------------
#define PLDX 40  // 32 + 8 pad (keeps 16B align, 2-way-max LDS conflicts)

__global__ __launch_bounds__(256) void qkv_kernel(
    const float* __restrict__ X, const unsigned short* __restrict__ Wt3,
    unsigned short* __restrict__ Qb, unsigned short* __restrict__ Kb,
    unsigned short* __restrict__ Vt) {
  __shared__ __align__(16) unsigned short Xs[128 * PLDX];
  __shared__ __align__(16) unsigned short Ws[128 * PLDX];
  const int tid = threadIdx.x;
  const int wv = tid >> 6;
  const int lane = tid & 63;
  const int l16 = lane & 15;
  const int quad = lane >> 4;
  const int m0 = blockIdx.x * 128;
  const int wy = blockIdx.y;
  const unsigned short* Wg = Wt3 + wy * (D_ * E_);

  floatx4 acc[2][8];
#pragma unroll
  for (int mt = 0; mt < 2; mt++)
#pragma unroll
    for (int nt = 0; nt < 8; nt++) acc[mt][nt] = (floatx4){0.f, 0.f, 0.f, 0.f};

  for (int k0 = 0; k0 < E_; k0 += 32) {
    // X tile 128x32 fp32 -> bf16 LDS. 1024 float4, 4/thread.
#pragma unroll
    for (int j = 0; j < 4; j++) {
      int id = tid + 256 * j;
      int row = id >> 3;
      int c4 = id & 7;
      float4 xv = *(const float4*)(X + (size_t)(m0 + row) * E_ + k0 + c4 * 4);
      ushort4 pk;
      pk.x = f2b(xv.x); pk.y = f2b(xv.y); pk.z = f2b(xv.z); pk.w = f2b(xv.w);
      *(ushort4*)&Xs[row * PLDX + c4 * 4] = pk;
    }
    // W tile (already bf16, transposed): 128 rows x 32 k. 512 uint4, 2/thread.
#pragma unroll
    for (int j = 0; j < 2; j++) {
      int id = tid + 256 * j;
      int row = id >> 2;
      int seg = id & 3;
      *(uint4*)&Ws[row * PLDX + seg * 8] =
          *(const uint4*)(Wg + (size_t)row * E_ + k0 + seg * 8);
    }
    __syncthreads();
    short8 af0 = *(const short8*)&Xs[(wv * 32 + l16) * PLDX + quad * 8];
    short8 af1 = *(const short8*)&Xs[(wv * 32 + 16 + l16) * PLDX + quad * 8];
#pragma unroll
    for (int nt = 0; nt < 8; nt++) {
      short8 bfr = *(const short8*)&Ws[(nt * 16 + l16) * PLDX + quad * 8];
      acc[0][nt] = __builtin_amdgcn_mfma_f32_16x16x32_bf16(af0, bfr, acc[0][nt], 0, 0, 0);
      acc[1][nt] = __builtin_amdgcn_mfma_f32_16x16x32_bf16(af1, bfr, acc[1][nt], 0, 0, 0);
    }
    __syncthreads();
  }

  // Epilogue. C/D layout: col = l16 (+16*nt), row = quad*4 + r  [m89-verified].
  if (wy < 2) {
    unsigned short* Og = (wy == 0) ? Qb : Kb;
#pragma unroll
    for (int mt = 0; mt < 2; mt++)
#pragma unroll
      for (int nt = 0; nt < 8; nt++)
#pragma unroll
        for (int r = 0; r < 4; r++) {
          int m = m0 + wv * 32 + mt * 16 + quad * 4 + r;
          int n = nt * 16 + l16;
          Og[(size_t)m * D_ + n] = f2b(acc[mt][nt][r]);
        }
  } else {
#pragma unroll
    for (int mt = 0; mt < 2; mt++)
#pragma unroll
      for (int nt = 0; nt < 8; nt++)
#pragma unroll
        for (int r = 0; r < 4; r++) {
          int tg = m0 + wv * 32 + mt * 16 + quad * 4 + r;
          int b = tg >> 11;
          int t = tg & (T_ - 1);
          int d = nt * 16 + l16;
          Vt[((size_t)(b * D_ + d)) * T_ + t] = f2b(acc[mt][nt][r]);
        }
  }
}

// ---------------------------------------------------------------------------
// Kernel 3: causal flash attention. BQ=32 (2 waves x 16 q-rows), BKV=64.
// S = Q*K^T via MFMA (Q pre-scaled by log2e/sqrt(128)); online softmax with
// exp2; P -> LDS (C/D->A layout round-trip, per m120); O += P*V via MFMA.
// Grid: 512 blocks, longest q-tile first for causal load balance.
// ---------------------------------------------------------------------------
#define KLD 136  // 128 + 8
#define VLD 72   // 64 + 8

__global__ __launch_bounds__(128) void attn_kernel(
    const unsigned short* __restrict__ Qb, const unsigned short* __restrict__ Kb,
    const unsigned short* __restrict__ Vt, float* __restrict__ Out) {
  __shared__ __align__(16) unsigned short Ks[64 * KLD];   // 17408 B
  __shared__ __align__(16) unsigned short Vs[128 * VLD];  // 18432 B (V^T tile)
  __shared__ __align__(16) unsigned short Qs[32 * KLD];   // 8704 B
  __shared__ __align__(16) unsigned short Ps[32 * VLD];   // 4608 B

  const int tid = threadIdx.x;
  const int wv = tid >> 6;  // 2 waves
  const int lane = tid & 63;
  const int l16 = lane & 15;
  const int quad = lane >> 4;

  const int bid = blockIdx.x;
  const int batch = bid & 7;
  const int qt = 63 - (bid >> 3);  // longest-first
  const int qb = qt * 32;

  const unsigned short* Qg = Qb + ((size_t)batch * T_ + qb) * D_;
  const unsigned short* Kg = Kb + (size_t)batch * T_ * D_;
  const unsigned short* Vg = Vt + (size_t)batch * D_ * T_;

  // Q tile 32x128 bf16: 512 uint4, 4/thread.
#pragma unroll
  for (int j = 0; j < 4; j++) {
    int id = tid + 128 * j;
    int row = id >> 4;
    int seg = id & 15;
    *(uint4*)&Qs[row * KLD + seg * 8] = *(const uint4*)(Qg + (size_t)row * D_ + seg * 8);
  }
  __syncthreads();
  short8 qf[4];  // A-operand: m = l16, k = quad*8 + j  [m120-verified]
#pragma unroll
  for (int f = 0; f < 4; f++)
    qf[f] = *(const short8*)&Qs[(wv * 16 + l16) * KLD + f * 32 + quad * 8];

  floatx4 oacc[8];
#pragma unroll
  for (int dt = 0; dt < 8; dt++) oacc[dt] = (floatx4){0.f, 0.f, 0.f, 0.f};
  float mrow[4], lrow[4];
#pragma unroll
  for (int r = 0; r < 4; r++) { mrow[r] = -1e30f; lrow[r] = 0.f; }

  const int niter = ((qb + 31) >> 6) + 1;
  for (int it = 0; it < niter; it++) {
    const int kb = it * 64;
    // K tile 64x128: 1024 uint4, 8/thread.
#pragma unroll
    for (int j = 0; j < 8; j++) {
      int id = tid + 128 * j;
      int row = id >> 4;
      int seg = id & 15;
      *(uint4*)&Ks[row * KLD + seg * 8] =
          *(const uint4*)(Kg + (size_t)(kb + row) * D_ + seg * 8);
    }
    // V^T tile 128(d) x 64(kv): 1024 uint4, 8/thread.
#pragma unroll
    for (int j = 0; j < 8; j++) {
      int id = tid + 128 * j;
      int row = id >> 3;
      int seg = id & 7;
      *(uint4*)&Vs[row * VLD + seg * 8] =
          *(const uint4*)(Vg + (size_t)row * T_ + kb + seg * 8);
    }
    __syncthreads();

    // S tile: wave's 16 q-rows x 64 kv. 16 MFMA.
    floatx4 sacc[4];
#pragma unroll
    for (int tn = 0; tn < 4; tn++) {
      floatx4 a = (floatx4){0.f, 0.f, 0.f, 0.f};
#pragma unroll
      for (int f = 0; f < 4; f++) {
        short8 bk = *(const short8*)&Ks[(tn * 16 + l16) * KLD + f * 32 + quad * 8];
        a = __builtin_amdgcn_mfma_f32_16x16x32_bf16(qf[f], bk, a, 0, 0, 0);
      }
      sacc[tn] = a;
    }

    // Causal mask (wave-uniform branch).
    if (kb + 63 > qb + wv * 16) {
#pragma unroll
      for (int tn = 0; tn < 4; tn++)
#pragma unroll
        for (int r = 0; r < 4; r++) {
          int col = kb + tn * 16 + l16;
          int rowg = qb + wv * 16 + quad * 4 + r;
          if (col > rowg) sacc[tn][r] = -1e30f;
        }
    }

    // Online softmax. Row r lives in the 16 lanes sharing `quad`.
#pragma unroll
    for (int r = 0; r < 4; r++) {
      float mx = fmaxf(fmaxf(sacc[0][r], sacc[1][r]), fmaxf(sacc[2][r], sacc[3][r]));
#pragma unroll
      for (int off = 8; off >= 1; off >>= 1)
        mx = fmaxf(mx, __shfl_xor(mx, off, 64));
      float mnew = fmaxf(mrow[r], mx);
      float alpha = EXP2F(mrow[r] - mnew);
      mrow[r] = mnew;
      float psum = 0.f;
#pragma unroll
      for (int tn = 0; tn < 4; tn++) {
        float p = EXP2F(sacc[tn][r] - mnew);
        sacc[tn][r] = p;
        psum += p;
      }
#pragma unroll
      for (int off = 8; off >= 1; off >>= 1)
        psum += __shfl_xor(psum, off, 64);
      lrow[r] = lrow[r] * alpha + psum;
#pragma unroll
      for (int dt = 0; dt < 8; dt++) oacc[dt][r] *= alpha;
    }

    // P (C/D layout) -> LDS -> A-operand layout. Per-wave region; DS ops are
    // in-order within a wave, no barrier needed before the re-read.
#pragma unroll
    for (int tn = 0; tn < 4; tn++)
#pragma unroll
      for (int r = 0; r < 4; r++)
        Ps[(wv * 16 + quad * 4 + r) * VLD + tn * 16 + l16] = f2b(sacc[tn][r]);

    short8 pa0 = *(const short8*)&Ps[(wv * 16 + l16) * VLD + quad * 8];
    short8 pa1 = *(const short8*)&Ps[(wv * 16 + l16) * VLD + 32 + quad * 8];
#pragma unroll
    for (int dt = 0; dt < 8; dt++) {
      short8 b0 = *(const short8*)&Vs[(dt * 16 + l16) * VLD + quad * 8];
      oacc[dt] = __builtin_amdgcn_mfma_f32_16x16x32_bf16(pa0, b0, oacc[dt], 0, 0, 0);
      short8 b1 = *(const short8*)&Vs[(dt * 16 + l16) * VLD + 32 + quad * 8];
      oacc[dt] = __builtin_amdgcn_mfma_f32_16x16x32_bf16(pa1, b1, oacc[dt], 0, 0, 0);
    }
    __syncthreads();  // protect Ks/Vs before next iteration's staging
  }

#pragma unroll
  for (int r = 0; r < 4; r++) lrow[r] = 1.f / lrow[r];
#pragma unroll
  for (int dt = 0; dt < 8; dt++)
#pragma unroll
    for (int r = 0; r < 4; r++) {
      int rowg = qb + wv * 16 + quad * 4 + r;
      Out[((size_t)batch * T_ + rowg) * D_ + dt * 16 + l16] = oacc[dt][r] * lrow[r];
    }
}

// ---------------------------------------------------------------------------
extern "C" void kernel_launch(void* const* d_in, const int* in_sizes, int n_in,
                              void* d_out, int out_size, void* d_ws, size_t ws_size,
                              hipStream_t stream) {
  const float* X  = (const float*)d_in[0];
  const float* Wq = (const float*)d_in[1];
  const float* Wk = (const float*)d_in[2];
  const float* Wv = (const float*)d_in[3];
  float* Out = (float*)d_out;

  char* ws = (char*)d_ws;
  unsigned short* Wt3 = (unsigned short*)(ws);                        // 768 KB
  unsigned short* Qb  = (unsigned short*)(ws + 786432);               // 4 MB
  unsigned short* Kb  = (unsigned short*)(ws + 786432 + 4194304);     // 4 MB
  unsigned short* Vt  = (unsigned short*)(ws + 786432 + 2 * 4194304); // 4 MB

  hipLaunchKernelGGL(wtrans_kernel, dim3(1536), dim3(256), 0, stream, Wq, Wk, Wv, Wt3);
  hipLaunchKernelGGL(qkv_kernel, dim3(128, 3), dim3(256), 0, stream, X, Wt3, Qb, Kb, Vt);
  hipLaunchKernelGGL(attn_kernel, dim3(512), dim3(128), 0, stream, Qb, Kb, Vt, Out);
}

// Round 2
// 187.324 us; speedup vs baseline: 1.0934x; 1.0934x over previous
//
#include <hip/hip_runtime.h>
#include <hip/hip_bf16.h>

#define B_ 8
#define T_ 2048
#define E_ 1024
#define D_ 128

typedef __attribute__((ext_vector_type(8))) short short8;
typedef __attribute__((ext_vector_type(4))) short short4v;
typedef __attribute__((ext_vector_type(4))) float floatx4;

__device__ __forceinline__ unsigned short f2b(float f) {
  union { float f; unsigned int u; } v; v.f = f;
  unsigned int u = v.u;
  return (unsigned short)((u + 0x7fffu + ((u >> 16) & 1u)) >> 16);  // RNE
}

#if defined(__has_builtin)
#if __has_builtin(__builtin_amdgcn_exp2f)
#define EXP2F(x) __builtin_amdgcn_exp2f(x)
#else
#define EXP2F(x) exp2f(x)
#endif
#else
#define EXP2F(x) exp2f(x)
#endif

// global -> LDS direct copy, 16B per lane. LDS dest = base + lane*16 (wave-
// uniform base). Swizzle is folded into the per-lane GLOBAL address.
__device__ __forceinline__ void gl_lds16(const unsigned short* g, unsigned short* l) {
  __builtin_amdgcn_global_load_lds(
      (const __attribute__((address_space(1))) unsigned int*)g,
      (__attribute__((address_space(3))) unsigned int*)l, 16, 0, 0);
}

// ---------------------------------------------------------------------------
// Kernel 1: W [1024x128] fp32 -> Wt3 [3][128][1024] bf16 (transposed).
// log2e/sqrt(128) folded into Wq so attn softmax uses exp2 directly.
// ---------------------------------------------------------------------------
__global__ __launch_bounds__(256) void wtrans_kernel(
    const float* __restrict__ Wq, const float* __restrict__ Wk,
    const float* __restrict__ Wv, unsigned short* __restrict__ Wt3) {
  int idx = blockIdx.x * 256 + threadIdx.x;
  if (idx >= 3 * E_ * D_) return;
  int w = idx / (E_ * D_);
  int rem = idx - w * (E_ * D_);
  int k = rem >> 7;
  int n = rem & (D_ - 1);
  const float* W = (w == 0) ? Wq : ((w == 1) ? Wk : Wv);
  float val = W[k * D_ + n];
  if (w == 0) val *= 1.4426950408889634f * 0.08838834764831845f;
  Wt3[w * (D_ * E_) + n * E_ + k] = f2b(val);
}

// ---------------------------------------------------------------------------
// Kernel 2: fused QKV. C[16384,384] = X[16384,1024]*W^T[1024,384], X read once.
// 256 blocks x 512 thr (8 waves). Tile 64 tokens x 384 ch; wave = 32 tok x 96 ch.
// X: fp32->bf16 VGPR staging (padded LDS). W: global_load_lds, XOR-swizzled.
// ---------------------------------------------------------------------------
#define XLD 40  // 32 + 8 pad

__global__ __launch_bounds__(512) void qkv_kernel(
    const float* __restrict__ X, const unsigned short* __restrict__ Wt3,
    unsigned short* __restrict__ Qb, unsigned short* __restrict__ Kb,
    unsigned short* __restrict__ Vt) {
  __shared__ __align__(16) unsigned short Xs[64 * XLD];   // 5.1 KB
  __shared__ __align__(16) unsigned short Ws[384 * 32];   // 24 KB, unpadded+swizzled
  const int tid = threadIdx.x;
  const int wv = tid >> 6;
  const int lane = tid & 63;
  const int l16 = lane & 15;
  const int quad = lane >> 4;
  const int wm = wv & 1;   // token half: rows wm*32..+31
  const int wn = wv >> 1;  // channel quarter: cols wn*96..+95
  const int m0 = blockIdx.x * 64;

  const int xrow = tid >> 3;       // X staging: 1 float4/thread
  const int xcol = (tid & 7) * 4;
  const int wrow_s = lane >> 2;    // W staging: 16 rows x 4 segs per inst
  const int wseg = lane & 3;
  const int wsw = (l16 >> 1) & 3;  // W read-side swizzle mask

  floatx4 acc[2][6];
#pragma unroll
  for (int mt = 0; mt < 2; mt++)
#pragma unroll
    for (int nt = 0; nt < 6; nt++) acc[mt][nt] = (floatx4){0.f, 0.f, 0.f, 0.f};

  for (int k0 = 0; k0 < E_; k0 += 32) {
    // X tile 64x32 fp32 -> bf16 (each thread one float4)
    float4 xv = *(const float4*)(X + (size_t)(m0 + xrow) * E_ + k0 + xcol);
    ushort4 pk;
    pk.x = f2b(xv.x); pk.y = f2b(xv.y); pk.z = f2b(xv.z); pk.w = f2b(xv.w);
    *(ushort4*)&Xs[xrow * XLD + xcol] = pk;
    // W tile 384x32 bf16 via global_load_lds: 24 insts, 3/wave.
#pragma unroll
    for (int j = 0; j < 3; j++) {
      int rbase = wv * 48 + j * 16;
      int row = rbase + wrow_s;
      int gseg = wseg ^ ((row >> 1) & 3);
      gl_lds16(Wt3 + (size_t)row * E_ + k0 + gseg * 8, &Ws[rbase * 32]);
    }
    __syncthreads();
    short8 af0 = *(const short8*)&Xs[(wm * 32 + l16) * XLD + quad * 8];
    short8 af1 = *(const short8*)&Xs[(wm * 32 + 16 + l16) * XLD + quad * 8];
#pragma unroll
    for (int nt = 0; nt < 6; nt++) {
      short8 bf = *(const short8*)&Ws[(wn * 96 + nt * 16 + l16) * 32 + (quad ^ wsw) * 8];
      acc[0][nt] = __builtin_amdgcn_mfma_f32_16x16x32_bf16(af0, bf, acc[0][nt], 0, 0, 0);
      acc[1][nt] = __builtin_amdgcn_mfma_f32_16x16x32_bf16(af1, bf, acc[1][nt], 0, 0, 0);
    }
    __syncthreads();
  }

  // Epilogue. C/D: col(n)=l16, row(m)=quad*4+r.
#pragma unroll
  for (int mt = 0; mt < 2; mt++)
#pragma unroll
    for (int nt = 0; nt < 6; nt++) {
      int n = wn * 96 + nt * 16 + l16;
      int w = n >> 7;
      int d = n & 127;
      int t0 = m0 + wm * 32 + mt * 16 + quad * 4;
      if (w == 0) {
#pragma unroll
        for (int r = 0; r < 4; r++) Qb[(size_t)(t0 + r) * D_ + d] = f2b(acc[mt][nt][r]);
      } else if (w == 1) {
#pragma unroll
        for (int r = 0; r < 4; r++) Kb[(size_t)(t0 + r) * D_ + d] = f2b(acc[mt][nt][r]);
      } else {
        int b = t0 >> 11;
        int t = t0 & (T_ - 1);
        short4v pv;
        pv.x = (short)f2b(acc[mt][nt][0]); pv.y = (short)f2b(acc[mt][nt][1]);
        pv.z = (short)f2b(acc[mt][nt][2]); pv.w = (short)f2b(acc[mt][nt][3]);
        *(short4v*)&Vt[((size_t)(b * D_ + d)) * T_ + t] = pv;
      }
    }
}

// ---------------------------------------------------------------------------
// Kernel 3: causal flash attention, S^T layout. BQ=32 (2 waves x 16 q), BKV=64.
// S^T = K.Q^T via operand-swapped MFMA: lane's column = its q-row -> softmax
// state is a lane scalar; only 2 shfl_xor steps per reduction.
// O^T = V^T.P accumulated in C-layout; transposed float4 epilogue store.
// Staging via global_load_lds, XOR-swizzle in global addr (2-way conflicts max).
// Blocks paired so each CU gets qt and 63-qt (balanced causal work).
// ---------------------------------------------------------------------------
#define PLD 72  // P tile leading dim (shorts)

__global__ __launch_bounds__(128) void attn_kernel(
    const unsigned short* __restrict__ Qb, const unsigned short* __restrict__ Kb,
    const unsigned short* __restrict__ Vt, float* __restrict__ Out) {
  __shared__ __align__(16) unsigned short Ks[64 * 128];  // 16 KB swizzled
  __shared__ __align__(16) unsigned short Vs[128 * 64];  // 16 KB swizzled (V^T)
  __shared__ __align__(16) unsigned short Qs[32 * 128];  // 8 KB swizzled
  __shared__ __align__(16) unsigned short Ps[32 * PLD];  // 4.6 KB padded

  const int tid = threadIdx.x;
  const int wv = tid >> 6;
  const int lane = tid & 63;
  const int l16 = lane & 15;
  const int quad = lane >> 4;

  const int bid = blockIdx.x;
  int batch, qt;
  if (bid < 256) { batch = bid & 7; qt = 63 - (bid >> 3); }
  else           { int b2 = bid - 256; batch = b2 & 7; qt = b2 >> 3; }
  const int qb = qt * 32;

  const unsigned short* Qg = Qb + ((size_t)batch * T_ + qb) * D_;
  const unsigned short* Kg = Kb + (size_t)batch * T_ * D_;
  const unsigned short* Vg = Vt + (size_t)batch * D_ * T_;

  // Q tile 32x128, swizzled: 4 global_load_lds per wave.
#pragma unroll
  for (int j = 0; j < 4; j++) {
    int rbase = wv * 16 + j * 4;
    int row = rbase + (lane >> 4);
    int gseg = (lane & 15) ^ (row & 15);
    gl_lds16(Qg + (size_t)row * D_ + gseg * 8, &Qs[rbase * 128]);
  }
  __syncthreads();
  short8 qf[4];  // B-operand for S^T: n=l16 (q), k=quad*8+j
#pragma unroll
  for (int f = 0; f < 4; f++)
    qf[f] = *(const short8*)&Qs[(wv * 16 + l16) * 128 + ((f * 4 + quad) ^ l16) * 8];

  floatx4 oacc[8];  // O^T: col=q=l16, row=d=dt*16+quad*4+r
#pragma unroll
  for (int dt = 0; dt < 8; dt++) oacc[dt] = (floatx4){0.f, 0.f, 0.f, 0.f};
  float mval = -1e30f, lval = 0.f;
  const int q_lane = qb + wv * 16 + l16;
  const int vsw = l16 & 7;

  const int niter = ((qb + 31) >> 6) + 1;
  for (int it = 0; it < niter; it++) {
    const int kb = it * 64;
    // K tile 64x128: 8 insts/wave.
#pragma unroll
    for (int j = 0; j < 8; j++) {
      int rbase = wv * 32 + j * 4;
      int row = rbase + (lane >> 4);
      int gseg = (lane & 15) ^ (row & 15);
      gl_lds16(Kg + (size_t)(kb + row) * D_ + gseg * 8, &Ks[rbase * 128]);
    }
    // V^T tile 128(d) x 64(kv): 8 insts/wave.
#pragma unroll
    for (int j = 0; j < 8; j++) {
      int rbase = wv * 64 + j * 8;
      int row = rbase + (lane >> 3);
      int gseg = (lane & 7) ^ (row & 7);
      gl_lds16(Vg + (size_t)row * T_ + kb + gseg * 8, &Vs[rbase * 64]);
    }
    __syncthreads();

    // S^T[kv][q]: A=K-frag (m=kv), B=qf. Lane: q=l16, kv=tn*16+quad*4+r.
    floatx4 sacc[4];
#pragma unroll
    for (int tn = 0; tn < 4; tn++) {
      floatx4 a = (floatx4){0.f, 0.f, 0.f, 0.f};
#pragma unroll
      for (int f = 0; f < 4; f++) {
        short8 bk = *(const short8*)&Ks[(tn * 16 + l16) * 128 + ((f * 4 + quad) ^ l16) * 8];
        a = __builtin_amdgcn_mfma_f32_16x16x32_bf16(bk, qf[f], a, 0, 0, 0);
      }
      sacc[tn] = a;
    }

    // Causal mask.
    if (kb + 63 > qb + wv * 16) {
#pragma unroll
      for (int tn = 0; tn < 4; tn++)
#pragma unroll
        for (int r = 0; r < 4; r++) {
          int kv = kb + tn * 16 + quad * 4 + r;
          if (kv > q_lane) sacc[tn][r] = -1e30f;
        }
    }

    // Online softmax: in-lane reduce over 16 vals, then xor-16/32 (quads).
    float mx = -1e30f;
#pragma unroll
    for (int tn = 0; tn < 4; tn++) {
      float a = fmaxf(sacc[tn][0], sacc[tn][1]);
      float b = fmaxf(sacc[tn][2], sacc[tn][3]);
      mx = fmaxf(mx, fmaxf(a, b));
    }
    mx = fmaxf(mx, __shfl_xor(mx, 16, 64));
    mx = fmaxf(mx, __shfl_xor(mx, 32, 64));
    float mnew = fmaxf(mval, mx);
    float alpha = EXP2F(mval - mnew);
    mval = mnew;
    float ps = 0.f;
#pragma unroll
    for (int tn = 0; tn < 4; tn++)
#pragma unroll
      for (int r = 0; r < 4; r++) {
        float p = EXP2F(sacc[tn][r] - mnew);
        sacc[tn][r] = p;
        ps += p;
      }
    ps += __shfl_xor(ps, 16, 64);
    ps += __shfl_xor(ps, 32, 64);
    lval = lval * alpha + ps;
#pragma unroll
    for (int dt = 0; dt < 8; dt++) {
      oacc[dt][0] *= alpha; oacc[dt][1] *= alpha;
      oacc[dt][2] *= alpha; oacc[dt][3] *= alpha;
    }

    // P^T pack: Ps[q][kv] (per-wave private rows; same-wave DS ops in order).
#pragma unroll
    for (int tn = 0; tn < 4; tn++) {
      short4v pk;
      pk.x = (short)f2b(sacc[tn][0]); pk.y = (short)f2b(sacc[tn][1]);
      pk.z = (short)f2b(sacc[tn][2]); pk.w = (short)f2b(sacc[tn][3]);
      *(short4v*)&Ps[(wv * 16 + l16) * PLD + tn * 16 + quad * 4] = pk;
    }

    // O^T += V^T.P: A=V^T-frag (m=d), B=P-frag (n=q=l16, k=quad*8+j).
#pragma unroll
    for (int half = 0; half < 2; half++) {
      short8 pf = *(const short8*)&Ps[(wv * 16 + l16) * PLD + half * 32 + quad * 8];
#pragma unroll
      for (int dt = 0; dt < 8; dt++) {
        short8 vf = *(const short8*)&Vs[(dt * 16 + l16) * 64 + ((half * 4 + quad) ^ vsw) * 8];
        oacc[dt] = __builtin_amdgcn_mfma_f32_16x16x32_bf16(vf, pf, oacc[dt], 0, 0, 0);
      }
    }
    __syncthreads();
  }

  float linv = 1.f / lval;
#pragma unroll
  for (int dt = 0; dt < 8; dt++) {
    float4 o;
    o.x = oacc[dt][0] * linv; o.y = oacc[dt][1] * linv;
    o.z = oacc[dt][2] * linv; o.w = oacc[dt][3] * linv;
    *(float4*)&Out[((size_t)batch * T_ + q_lane) * D_ + dt * 16 + quad * 4] = o;
  }
}

// ---------------------------------------------------------------------------
extern "C" void kernel_launch(void* const* d_in, const int* in_sizes, int n_in,
                              void* d_out, int out_size, void* d_ws, size_t ws_size,
                              hipStream_t stream) {
  const float* X  = (const float*)d_in[0];
  const float* Wq = (const float*)d_in[1];
  const float* Wk = (const float*)d_in[2];
  const float* Wv = (const float*)d_in[3];
  float* Out = (float*)d_out;

  char* ws = (char*)d_ws;
  unsigned short* Wt3 = (unsigned short*)(ws);                        // 768 KB
  unsigned short* Qb  = (unsigned short*)(ws + 786432);               // 4 MB
  unsigned short* Kb  = (unsigned short*)(ws + 786432 + 4194304);     // 4 MB
  unsigned short* Vt  = (unsigned short*)(ws + 786432 + 2 * 4194304); // 4 MB

  hipLaunchKernelGGL(wtrans_kernel, dim3(1536), dim3(256), 0, stream, Wq, Wk, Wv, Wt3);
  hipLaunchKernelGGL(qkv_kernel, dim3(256), dim3(512), 0, stream, X, Wt3, Qb, Kb, Vt);
  hipLaunchKernelGGL(attn_kernel, dim3(512), dim3(128), 0, stream, Qb, Kb, Vt, Out);
}

// Round 3
// 186.833 us; speedup vs baseline: 1.0963x; 1.0026x over previous
//
#include <hip/hip_runtime.h>
#include <hip/hip_bf16.h>

#define B_ 8
#define T_ 2048
#define E_ 1024
#define D_ 128

typedef __attribute__((ext_vector_type(8))) short short8;
typedef __attribute__((ext_vector_type(4))) short short4v;
typedef __attribute__((ext_vector_type(4))) float floatx4;

__device__ __forceinline__ unsigned short f2b(float f) {
  union { float f; unsigned int u; } v; v.f = f;
  unsigned int u = v.u;
  return (unsigned short)((u + 0x7fffu + ((u >> 16) & 1u)) >> 16);  // RNE
}

#if defined(__has_builtin)
#if __has_builtin(__builtin_amdgcn_exp2f)
#define EXP2F(x) __builtin_amdgcn_exp2f(x)
#else
#define EXP2F(x) exp2f(x)
#endif
#else
#define EXP2F(x) exp2f(x)
#endif

__device__ __forceinline__ void gl_lds16(const unsigned short* g, unsigned short* l) {
  __builtin_amdgcn_global_load_lds(
      (const __attribute__((address_space(1))) unsigned int*)g,
      (__attribute__((address_space(3))) unsigned int*)l, 16, 0, 0);
}

// ---------------------------------------------------------------------------
// Kernel 1: W [1024x128] fp32 -> Wt3 [3][128][1024] bf16 via LDS-tile
// transpose (coalesced reads AND writes; old version had 2B stride-2KB
// scattered stores = 32x write amplification).
// Tile: 128 k x 32 n. Grid: 3 x 8 x 4 = 96 blocks x 256 threads.
// ---------------------------------------------------------------------------
__global__ __launch_bounds__(256) void wtrans_kernel(
    const float* __restrict__ Wq, const float* __restrict__ Wk,
    const float* __restrict__ Wv, unsigned short* __restrict__ Wt3) {
  __shared__ __align__(16) unsigned short Tls[32][136];  // [n][k], 272B rows
  const int tid = threadIdx.x;
  const int w = blockIdx.x >> 5;
  const int rem = blockIdx.x & 31;
  const int k0 = (rem >> 2) * 128;
  const int n0 = (rem & 3) * 32;
  const float* W = (w == 0) ? Wq : ((w == 1) ? Wk : Wv);
  const float scale = (w == 0) ? (1.4426950408889634f * 0.08838834764831845f) : 1.0f;
#pragma unroll
  for (int j = 0; j < 4; j++) {
    int id = tid + 256 * j;      // 1024 float4s = 128k x 32n
    int k = id >> 3;
    int nn = (id & 7) * 4;
    float4 v = *(const float4*)(W + (size_t)(k0 + k) * D_ + n0 + nn);
    Tls[nn + 0][k] = f2b(v.x * scale);
    Tls[nn + 1][k] = f2b(v.y * scale);
    Tls[nn + 2][k] = f2b(v.z * scale);
    Tls[nn + 3][k] = f2b(v.w * scale);
  }
  __syncthreads();
#pragma unroll
  for (int j = 0; j < 2; j++) {
    int id = tid + 256 * j;      // 512 x 16B segs = 32n x 128k shorts
    int n = id >> 4;
    int seg = id & 15;
    short8 o = *(const short8*)&Tls[n][seg * 8];
    *(short8*)&Wt3[(size_t)w * D_ * E_ + (size_t)(n0 + n) * E_ + k0 + seg * 8] = o;
  }
}

// ---------------------------------------------------------------------------
// Kernel 2: fused QKV, software-pipelined. C[16384,384]=X[16384,1024]*W^T.
// 256 blocks x 512 thr (8 waves); tile 64 tok x 384 ch; BK=32; DOUBLE-BUFFERED
// LDS, one barrier/iter: issue X(i+1)->regs + W(i+1)->glds(!cur) BEFORE
// computing tile i, so load latency hides behind 12 MFMA/wave of compute.
// ---------------------------------------------------------------------------
#define XLD 40  // 32 + 8 pad

__global__ __launch_bounds__(512) void qkv_kernel(
    const float* __restrict__ X, const unsigned short* __restrict__ Wt3,
    unsigned short* __restrict__ Qb, unsigned short* __restrict__ Kb,
    unsigned short* __restrict__ Vt) {
  __shared__ __align__(16) unsigned short Xs[2][64 * XLD];   // 2 x 5.1 KB
  __shared__ __align__(16) unsigned short Ws[2][384 * 32];   // 2 x 24 KB
  const int tid = threadIdx.x;
  const int wv = tid >> 6;
  const int lane = tid & 63;
  const int l16 = lane & 15;
  const int quad = lane >> 4;
  const int wm = wv & 1;
  const int wn = wv >> 1;
  const int m0 = blockIdx.x * 64;

  const int xrow = tid >> 3;
  const int xcol = (tid & 7) * 4;
  const int wrow_s = lane >> 2;
  const int wseg = lane & 3;
  const int wsw = (l16 >> 1) & 3;

  floatx4 acc[2][6];
#pragma unroll
  for (int mt = 0; mt < 2; mt++)
#pragma unroll
    for (int nt = 0; nt < 6; nt++) acc[mt][nt] = (floatx4){0.f, 0.f, 0.f, 0.f};

  // prologue: stage tile 0 into buffer 0
  {
    float4 xv = *(const float4*)(X + (size_t)(m0 + xrow) * E_ + xcol);
#pragma unroll
    for (int j = 0; j < 3; j++) {
      int rbase = wv * 48 + j * 16;
      int row = rbase + wrow_s;
      int gseg = wseg ^ ((row >> 1) & 3);
      gl_lds16(Wt3 + (size_t)row * E_ + gseg * 8, &Ws[0][rbase * 32]);
    }
    ushort4 pk;
    pk.x = f2b(xv.x); pk.y = f2b(xv.y); pk.z = f2b(xv.z); pk.w = f2b(xv.w);
    *(ushort4*)&Xs[0][xrow * XLD + xcol] = pk;
  }
  __syncthreads();

  int cur = 0;
  for (int i = 0; i < 32; i++) {
    // 1. prefetch tile i+1 (global->regs for X, glds for W) into !cur
    float4 xn;
    if (i < 31) {
      int k0n = (i + 1) * 32;
      xn = *(const float4*)(X + (size_t)(m0 + xrow) * E_ + k0n + xcol);
#pragma unroll
      for (int j = 0; j < 3; j++) {
        int rbase = wv * 48 + j * 16;
        int row = rbase + wrow_s;
        int gseg = wseg ^ ((row >> 1) & 3);
        gl_lds16(Wt3 + (size_t)row * E_ + k0n + gseg * 8, &Ws[cur ^ 1][rbase * 32]);
      }
    }
    // 2. compute tile i
    short8 af0 = *(const short8*)&Xs[cur][(wm * 32 + l16) * XLD + quad * 8];
    short8 af1 = *(const short8*)&Xs[cur][(wm * 32 + 16 + l16) * XLD + quad * 8];
#pragma unroll
    for (int nt = 0; nt < 6; nt++) {
      short8 bf = *(const short8*)&Ws[cur][(wn * 96 + nt * 16 + l16) * 32 + (quad ^ wsw) * 8];
      acc[0][nt] = __builtin_amdgcn_mfma_f32_16x16x32_bf16(af0, bf, acc[0][nt], 0, 0, 0);
      acc[1][nt] = __builtin_amdgcn_mfma_f32_16x16x32_bf16(af1, bf, acc[1][nt], 0, 0, 0);
    }
    // 3. convert+store prefetched X (vmcnt wait lands here, after compute)
    if (i < 31) {
      ushort4 pk;
      pk.x = f2b(xn.x); pk.y = f2b(xn.y); pk.z = f2b(xn.z); pk.w = f2b(xn.w);
      *(ushort4*)&Xs[cur ^ 1][xrow * XLD + xcol] = pk;
    }
    __syncthreads();
    cur ^= 1;
  }

  // Epilogue. C/D: col(n)=l16, row(m)=quad*4+r.
#pragma unroll
  for (int mt = 0; mt < 2; mt++)
#pragma unroll
    for (int nt = 0; nt < 6; nt++) {
      int n = wn * 96 + nt * 16 + l16;
      int w = n >> 7;
      int d = n & 127;
      int t0 = m0 + wm * 32 + mt * 16 + quad * 4;
      if (w == 0) {
#pragma unroll
        for (int r = 0; r < 4; r++) Qb[(size_t)(t0 + r) * D_ + d] = f2b(acc[mt][nt][r]);
      } else if (w == 1) {
#pragma unroll
        for (int r = 0; r < 4; r++) Kb[(size_t)(t0 + r) * D_ + d] = f2b(acc[mt][nt][r]);
      } else {
        int b = t0 >> 11;
        int t = t0 & (T_ - 1);
        short4v pv;
        pv.x = (short)f2b(acc[mt][nt][0]); pv.y = (short)f2b(acc[mt][nt][1]);
        pv.z = (short)f2b(acc[mt][nt][2]); pv.w = (short)f2b(acc[mt][nt][3]);
        *(short4v*)&Vt[((size_t)(b * D_ + d)) * T_ + t] = pv;
      }
    }
}

// ---------------------------------------------------------------------------
// Kernel 3: causal flash attention, S^T layout, K/V DOUBLE-BUFFERED.
// BQ=32 (2 waves x 16 q), BKV=64. Prefetch kv(i+1) via glds before computing
// kv(i); one barrier/iter. LDS 78 KB -> 2 blocks/CU (matches grid 512).
// ---------------------------------------------------------------------------
#define PLD 72

__global__ __launch_bounds__(128) void attn_kernel(
    const unsigned short* __restrict__ Qb, const unsigned short* __restrict__ Kb,
    const unsigned short* __restrict__ Vt, float* __restrict__ Out) {
  __shared__ __align__(16) unsigned short Ks[2][64 * 128];  // 2 x 16 KB
  __shared__ __align__(16) unsigned short Vs[2][128 * 64];  // 2 x 16 KB
  __shared__ __align__(16) unsigned short Qs[32 * 128];     // 8 KB
  __shared__ __align__(16) unsigned short Ps[32 * PLD];     // 4.6 KB

  const int tid = threadIdx.x;
  const int wv = tid >> 6;
  const int lane = tid & 63;
  const int l16 = lane & 15;
  const int quad = lane >> 4;

  const int bid = blockIdx.x;
  int batch, qt;
  if (bid < 256) { batch = bid & 7; qt = 63 - (bid >> 3); }
  else           { int b2 = bid - 256; batch = b2 & 7; qt = b2 >> 3; }
  const int qb = qt * 32;

  const unsigned short* Qg = Qb + ((size_t)batch * T_ + qb) * D_;
  const unsigned short* Kg = Kb + (size_t)batch * T_ * D_;
  const unsigned short* Vg = Vt + (size_t)batch * D_ * T_;

  // prologue: Q tile + kv tile 0
#pragma unroll
  for (int j = 0; j < 4; j++) {
    int rbase = wv * 16 + j * 4;
    int row = rbase + (lane >> 4);
    int gseg = (lane & 15) ^ (row & 15);
    gl_lds16(Qg + (size_t)row * D_ + gseg * 8, &Qs[rbase * 128]);
  }
#pragma unroll
  for (int j = 0; j < 8; j++) {
    int rbase = wv * 32 + j * 4;
    int row = rbase + (lane >> 4);
    int gseg = (lane & 15) ^ (row & 15);
    gl_lds16(Kg + (size_t)row * D_ + gseg * 8, &Ks[0][rbase * 128]);
  }
#pragma unroll
  for (int j = 0; j < 8; j++) {
    int rbase = wv * 64 + j * 8;
    int row = rbase + (lane >> 3);
    int gseg = (lane & 7) ^ (row & 7);
    gl_lds16(Vg + (size_t)row * T_ + gseg * 8, &Vs[0][rbase * 64]);
  }
  __syncthreads();

  short8 qf[4];  // B-operand: n=l16 (q), k=quad*8+j
#pragma unroll
  for (int f = 0; f < 4; f++)
    qf[f] = *(const short8*)&Qs[(wv * 16 + l16) * 128 + ((f * 4 + quad) ^ l16) * 8];

  floatx4 oacc[8];  // O^T: col=q=l16, row=d=dt*16+quad*4+r
#pragma unroll
  for (int dt = 0; dt < 8; dt++) oacc[dt] = (floatx4){0.f, 0.f, 0.f, 0.f};
  float mval = -1e30f, lval = 0.f;
  const int q_lane = qb + wv * 16 + l16;
  const int vsw = l16 & 7;

  const int niter = ((qb + 31) >> 6) + 1;
  int cur = 0;
  for (int it = 0; it < niter; it++) {
    const int kb = it * 64;
    // prefetch kv(it+1) into !cur
    if (it + 1 < niter) {
      const int kbn = kb + 64;
#pragma unroll
      for (int j = 0; j < 8; j++) {
        int rbase = wv * 32 + j * 4;
        int row = rbase + (lane >> 4);
        int gseg = (lane & 15) ^ (row & 15);
        gl_lds16(Kg + (size_t)(kbn + row) * D_ + gseg * 8, &Ks[cur ^ 1][rbase * 128]);
      }
#pragma unroll
      for (int j = 0; j < 8; j++) {
        int rbase = wv * 64 + j * 8;
        int row = rbase + (lane >> 3);
        int gseg = (lane & 7) ^ (row & 7);
        gl_lds16(Vg + (size_t)row * T_ + kbn + gseg * 8, &Vs[cur ^ 1][rbase * 64]);
      }
    }

    // S^T[kv][q]: A=K-frag (m=kv), B=qf. Lane: q=l16, kv=tn*16+quad*4+r.
    floatx4 sacc[4];
#pragma unroll
    for (int tn = 0; tn < 4; tn++) {
      floatx4 a = (floatx4){0.f, 0.f, 0.f, 0.f};
#pragma unroll
      for (int f = 0; f < 4; f++) {
        short8 bk = *(const short8*)&Ks[cur][(tn * 16 + l16) * 128 + ((f * 4 + quad) ^ l16) * 8];
        a = __builtin_amdgcn_mfma_f32_16x16x32_bf16(bk, qf[f], a, 0, 0, 0);
      }
      sacc[tn] = a;
    }

    if (kb + 63 > qb + wv * 16) {
#pragma unroll
      for (int tn = 0; tn < 4; tn++)
#pragma unroll
        for (int r = 0; r < 4; r++) {
          int kv = kb + tn * 16 + quad * 4 + r;
          if (kv > q_lane) sacc[tn][r] = -1e30f;
        }
    }

    // online softmax: lane-local reduce + 2 shfl_xor (quad halves)
    float mx = -1e30f;
#pragma unroll
    for (int tn = 0; tn < 4; tn++) {
      float a = fmaxf(sacc[tn][0], sacc[tn][1]);
      float b = fmaxf(sacc[tn][2], sacc[tn][3]);
      mx = fmaxf(mx, fmaxf(a, b));
    }
    mx = fmaxf(mx, __shfl_xor(mx, 16, 64));
    mx = fmaxf(mx, __shfl_xor(mx, 32, 64));
    float mnew = fmaxf(mval, mx);
    float alpha = EXP2F(mval - mnew);
    mval = mnew;
    float ps = 0.f;
#pragma unroll
    for (int tn = 0; tn < 4; tn++)
#pragma unroll
      for (int r = 0; r < 4; r++) {
        float p = EXP2F(sacc[tn][r] - mnew);
        sacc[tn][r] = p;
        ps += p;
      }
    ps += __shfl_xor(ps, 16, 64);
    ps += __shfl_xor(ps, 32, 64);
    lval = lval * alpha + ps;
#pragma unroll
    for (int dt = 0; dt < 8; dt++) {
      oacc[dt][0] *= alpha; oacc[dt][1] *= alpha;
      oacc[dt][2] *= alpha; oacc[dt][3] *= alpha;
    }

    // P^T pack (per-wave private rows; same-wave DS ops in order)
#pragma unroll
    for (int tn = 0; tn < 4; tn++) {
      short4v pk;
      pk.x = (short)f2b(sacc[tn][0]); pk.y = (short)f2b(sacc[tn][1]);
      pk.z = (short)f2b(sacc[tn][2]); pk.w = (short)f2b(sacc[tn][3]);
      *(short4v*)&Ps[(wv * 16 + l16) * PLD + tn * 16 + quad * 4] = pk;
    }

    // O^T += V^T.P
#pragma unroll
    for (int half = 0; half < 2; half++) {
      short8 pf = *(const short8*)&Ps[(wv * 16 + l16) * PLD + half * 32 + quad * 8];
#pragma unroll
      for (int dt = 0; dt < 8; dt++) {
        short8 vf = *(const short8*)&Vs[cur][(dt * 16 + l16) * 64 + ((half * 4 + quad) ^ vsw) * 8];
        oacc[dt] = __builtin_amdgcn_mfma_f32_16x16x32_bf16(vf, pf, oacc[dt], 0, 0, 0);
      }
    }
    __syncthreads();
    cur ^= 1;
  }

  float linv = 1.f / lval;
#pragma unroll
  for (int dt = 0; dt < 8; dt++) {
    float4 o;
    o.x = oacc[dt][0] * linv; o.y = oacc[dt][1] * linv;
    o.z = oacc[dt][2] * linv; o.w = oacc[dt][3] * linv;
    *(float4*)&Out[((size_t)batch * T_ + q_lane) * D_ + dt * 16 + quad * 4] = o;
  }
}

// ---------------------------------------------------------------------------
extern "C" void kernel_launch(void* const* d_in, const int* in_sizes, int n_in,
                              void* d_out, int out_size, void* d_ws, size_t ws_size,
                              hipStream_t stream) {
  const float* X  = (const float*)d_in[0];
  const float* Wq = (const float*)d_in[1];
  const float* Wk = (const float*)d_in[2];
  const float* Wv = (const float*)d_in[3];
  float* Out = (float*)d_out;

  char* ws = (char*)d_ws;
  unsigned short* Wt3 = (unsigned short*)(ws);                        // 768 KB
  unsigned short* Qb  = (unsigned short*)(ws + 786432);               // 4 MB
  unsigned short* Kb  = (unsigned short*)(ws + 786432 + 4194304);     // 4 MB
  unsigned short* Vt  = (unsigned short*)(ws + 786432 + 2 * 4194304); // 4 MB

  hipLaunchKernelGGL(wtrans_kernel, dim3(96), dim3(256), 0, stream, Wq, Wk, Wv, Wt3);
  hipLaunchKernelGGL(qkv_kernel, dim3(256), dim3(512), 0, stream, X, Wt3, Qb, Kb, Vt);
  hipLaunchKernelGGL(attn_kernel, dim3(512), dim3(128), 0, stream, Qb, Kb, Vt, Out);
}

// Round 4
// 161.947 us; speedup vs baseline: 1.2647x; 1.1537x over previous
//
#include <hip/hip_runtime.h>
#include <hip/hip_bf16.h>

#define B_ 8
#define T_ 2048
#define E_ 1024
#define D_ 128

typedef __attribute__((ext_vector_type(8))) short short8;
typedef __attribute__((ext_vector_type(4))) short short4v;
typedef __attribute__((ext_vector_type(4))) float floatx4;
typedef __attribute__((ext_vector_type(16))) float floatx16;

__device__ __forceinline__ unsigned short f2b(float f) {
  union { float f; unsigned int u; } v; v.f = f;
  unsigned int u = v.u;
  return (unsigned short)((u + 0x7fffu + ((u >> 16) & 1u)) >> 16);  // RNE
}

#if defined(__has_builtin)
#if __has_builtin(__builtin_amdgcn_exp2f)
#define EXP2F(x) __builtin_amdgcn_exp2f(x)
#else
#define EXP2F(x) exp2f(x)
#endif
#else
#define EXP2F(x) exp2f(x)
#endif

// gfx9-style waitcnt immediates: vmcnt[3:0]+[15:14], expcnt[6:4], lgkmcnt[11:8]
#define WAIT_LGKM0()  __builtin_amdgcn_s_waitcnt(0xC07F)  // lgkmcnt(0)
#define WAIT_VM0()    __builtin_amdgcn_s_waitcnt(0x0F70)  // vmcnt(0)
#define WAIT_VM16()   __builtin_amdgcn_s_waitcnt(0x4F70)  // vmcnt(16)

__device__ __forceinline__ void gl_lds16(const unsigned short* g, unsigned short* l) {
  __builtin_amdgcn_global_load_lds(
      (const __attribute__((address_space(1))) unsigned int*)g,
      (__attribute__((address_space(3))) unsigned int*)l, 16, 0, 0);
}

// ---------------------------------------------------------------------------
// Kernel 1: W [1024x128] fp32 -> Wt3 [3][128][1024] bf16 via LDS transpose.
// log2e/sqrt(128) folded into Wq (attn softmax then uses exp2 directly).
// ---------------------------------------------------------------------------
__global__ __launch_bounds__(256) void wtrans_kernel(
    const float* __restrict__ Wq, const float* __restrict__ Wk,
    const float* __restrict__ Wv, unsigned short* __restrict__ Wt3) {
  __shared__ __align__(16) unsigned short Tls[32][136];
  const int tid = threadIdx.x;
  const int w = blockIdx.x >> 5;
  const int rem = blockIdx.x & 31;
  const int k0 = (rem >> 2) * 128;
  const int n0 = (rem & 3) * 32;
  const float* W = (w == 0) ? Wq : ((w == 1) ? Wk : Wv);
  const float scale = (w == 0) ? (1.4426950408889634f * 0.08838834764831845f) : 1.0f;
#pragma unroll
  for (int j = 0; j < 4; j++) {
    int id = tid + 256 * j;
    int k = id >> 3;
    int nn = (id & 7) * 4;
    float4 v = *(const float4*)(W + (size_t)(k0 + k) * D_ + n0 + nn);
    Tls[nn + 0][k] = f2b(v.x * scale);
    Tls[nn + 1][k] = f2b(v.y * scale);
    Tls[nn + 2][k] = f2b(v.z * scale);
    Tls[nn + 3][k] = f2b(v.w * scale);
  }
  __syncthreads();
#pragma unroll
  for (int j = 0; j < 2; j++) {
    int id = tid + 256 * j;
    int n = id >> 4;
    int seg = id & 15;
    short8 o = *(const short8*)&Tls[n][seg * 8];
    *(short8*)&Wt3[(size_t)w * D_ * E_ + (size_t)(n0 + n) * E_ + k0 + seg * 8] = o;
  }
}

// ---------------------------------------------------------------------------
// Kernel 2: fused QKV. 512 blocks x 256 thr (4 waves) -> 3 blocks/CU (53KB
// LDS): barrier drains covered by sibling blocks (m97 structure). Tile:
// 32 tok x 384 ch, BK=64; wave = 32 tok x 96 ch = 24 MFMA per iter, 16 iters.
// X: reg-prefetched fp32->bf16; W: global_load_lds, XOR-swizzled.
// ---------------------------------------------------------------------------
#define XLD 72  // 64 + 8 pad (shorts)

__global__ __launch_bounds__(256) void qkv_kernel(
    const float* __restrict__ X, const unsigned short* __restrict__ Wt3,
    unsigned short* __restrict__ Qb, unsigned short* __restrict__ Kb,
    unsigned short* __restrict__ Vt) {
  __shared__ __align__(16) unsigned short Xs[32 * XLD];   // 4.5 KB
  __shared__ __align__(16) unsigned short Ws[384 * 64];   // 48 KB swizzled
  const int tid = threadIdx.x;
  const int wv = tid >> 6;
  const int lane = tid & 63;
  const int l16 = lane & 15;
  const int quad = lane >> 4;
  const int m0 = blockIdx.x * 32;

  const int xrow = tid >> 4;        // 0..15 (j adds 16)
  const int xcol = (tid & 15) * 4;  // float col 0..60
  const int wrow_off = lane >> 3;
  const int wslot = lane & 7;

  floatx4 acc[2][6];
#pragma unroll
  for (int mt = 0; mt < 2; mt++)
#pragma unroll
    for (int nt = 0; nt < 6; nt++) acc[mt][nt] = (floatx4){0.f, 0.f, 0.f, 0.f};

  // prologue: X(0) into regs
  float4 xr0 = *(const float4*)(X + (size_t)(m0 + xrow) * E_ + xcol);
  float4 xr1 = *(const float4*)(X + (size_t)(m0 + 16 + xrow) * E_ + xcol);

  for (int i = 0; i < 16; i++) {
    if (i) __syncthreads();  // compute(i-1) done reading LDS
    const int k0 = i * 64;
    // store prefetched X (converted)
    {
      ushort4 p0, p1;
      p0.x = f2b(xr0.x); p0.y = f2b(xr0.y); p0.z = f2b(xr0.z); p0.w = f2b(xr0.w);
      p1.x = f2b(xr1.x); p1.y = f2b(xr1.y); p1.z = f2b(xr1.z); p1.w = f2b(xr1.w);
      *(ushort4*)&Xs[xrow * XLD + xcol] = p0;
      *(ushort4*)&Xs[(16 + xrow) * XLD + xcol] = p1;
    }
    // W tile 384x64 via glds: 12 insts/thread (8 rows each)
#pragma unroll
    for (int j = 0; j < 12; j++) {
      int rbase = wv * 96 + j * 8;
      int row = rbase + wrow_off;
      int gseg = wslot ^ (row & 7);
      gl_lds16(Wt3 + (size_t)row * E_ + k0 + gseg * 8, &Ws[rbase * 64]);
    }
    __syncthreads();  // staging visible (drains glds too)
    // prefetch X(i+1) into regs (consumed after next barrier)
    if (i < 15) {
      xr0 = *(const float4*)(X + (size_t)(m0 + xrow) * E_ + k0 + 64 + xcol);
      xr1 = *(const float4*)(X + (size_t)(m0 + 16 + xrow) * E_ + k0 + 64 + xcol);
    }
    // compute: 2 mt x 6 nt x 2 kf = 24 MFMA
    short8 af[2][2];
#pragma unroll
    for (int mt = 0; mt < 2; mt++)
#pragma unroll
      for (int kf = 0; kf < 2; kf++)
        af[mt][kf] = *(const short8*)&Xs[(mt * 16 + l16) * XLD + kf * 32 + quad * 8];
#pragma unroll
    for (int nt = 0; nt < 6; nt++) {
      int n = wv * 96 + nt * 16 + l16;
#pragma unroll
      for (int kf = 0; kf < 2; kf++) {
        short8 bf = *(const short8*)&Ws[n * 64 + ((kf * 4 + quad) ^ (l16 & 7)) * 8];
        acc[0][nt] = __builtin_amdgcn_mfma_f32_16x16x32_bf16(af[0][kf], bf, acc[0][nt], 0, 0, 0);
        acc[1][nt] = __builtin_amdgcn_mfma_f32_16x16x32_bf16(af[1][kf], bf, acc[1][nt], 0, 0, 0);
      }
    }
  }

  // Epilogue. C/D: col(n)=l16, row(m)=quad*4+r.
#pragma unroll
  for (int mt = 0; mt < 2; mt++)
#pragma unroll
    for (int nt = 0; nt < 6; nt++) {
      int n = wv * 96 + nt * 16 + l16;
      int w = n >> 7;
      int d = n & 127;
      int t0 = m0 + mt * 16 + quad * 4;
      if (w == 0) {
#pragma unroll
        for (int r = 0; r < 4; r++) Qb[(size_t)(t0 + r) * D_ + d] = f2b(acc[mt][nt][r]);
      } else if (w == 1) {
#pragma unroll
        for (int r = 0; r < 4; r++) Kb[(size_t)(t0 + r) * D_ + d] = f2b(acc[mt][nt][r]);
      } else {
        int b = t0 >> 11;
        int t = t0 & (T_ - 1);
        short4v pv;
        pv.x = (short)f2b(acc[mt][nt][0]); pv.y = (short)f2b(acc[mt][nt][1]);
        pv.z = (short)f2b(acc[mt][nt][2]); pv.w = (short)f2b(acc[mt][nt][3]);
        *(short4v*)&Vt[((size_t)(b * D_ + d)) * T_ + t] = pv;
      }
    }
}

// ---------------------------------------------------------------------------
// Kernel 3: causal flash attention, barrier-free waves. 512 blocks x 128 thr.
// Block = (batch, 32-q tile); its 2 waves split KV chunks even/odd (flash-
// decode within block), each with PRIVATE K/V/P LDS; no __syncthreads in the
// loop — explicit s_waitcnt only (K-wait split from V-wait). 32x32x16 MFMA:
// S^T = K.Q^T puts a q-row in lanes {q,q+32} -> softmax = 1 shfl_xor.
// One barrier total for the m/l/O merge. Blocks paired (qt, 63-qt).
// ---------------------------------------------------------------------------
#define PLD2 72
#define KSZ (64 * 128)
#define VSZ (128 * 64)
#define WBUF (KSZ + VSZ + 32 * PLD2)  // 18688 shorts per wave

__global__ __launch_bounds__(128) void attn_kernel(
    const unsigned short* __restrict__ Qb, const unsigned short* __restrict__ Kb,
    const unsigned short* __restrict__ Vt, float* __restrict__ Out) {
  __shared__ __align__(16) unsigned short Buf[2][WBUF];  // 73 KB
  __shared__ float Ms[32], Ls[32];

  const int tid = threadIdx.x;
  const int wv = tid >> 6;
  const int lane = tid & 63;
  const int l32 = lane & 31;
  const int hi = lane >> 5;

  const int idx = blockIdx.x >> 1;
  const int batch = idx & 7;
  const int qh = idx >> 3;  // 0..31
  const int qt = (blockIdx.x & 1) ? (63 - qh) : qh;
  const int qb = qt * 32;

  unsigned short* Ks = &Buf[wv][0];
  unsigned short* Vs = &Buf[wv][KSZ];
  unsigned short* Ps = &Buf[wv][KSZ + VSZ];

  const unsigned short* Kg = Kb + (size_t)batch * T_ * D_;
  const unsigned short* Vg = Vt + (size_t)batch * D_ * T_;
  const int qg = qb + l32;

  // Q B-frags direct from global: B[k][n]: n=l32, k=kf*16+hi*8+j
  short8 qf[8];
#pragma unroll
  for (int kf = 0; kf < 8; kf++)
    qf[kf] = *(const short8*)(Qb + ((size_t)batch * T_ + qg) * D_ + kf * 16 + hi * 8);

  floatx16 oacc[4];  // O^T: col q=l32, row d=dt*32+(r&3)+8*(r>>2)+4*hi
#pragma unroll
  for (int dt = 0; dt < 4; dt++)
#pragma unroll
    for (int r = 0; r < 16; r++) oacc[dt][r] = 0.f;
  float mval = -1e30f, lval = 0.f;

  const int niter = ((qb + 31) >> 6) + 1;
  for (int it = wv; it < niter; it += 2) {
    const int kb = it * 64;
    WAIT_LGKM0();  // prior ds_reads retired before glds overwrites our buffers
    // K tile 64x128 (16 glds), then V^T tile 128x64 (16 glds)
#pragma unroll
    for (int j = 0; j < 16; j++) {
      int rbase = j * 4;
      int row = rbase + (lane >> 4);
      int gseg = (lane & 15) ^ (row & 15);
      gl_lds16(Kg + (size_t)(kb + row) * D_ + gseg * 8, &Ks[rbase * 128]);
    }
#pragma unroll
    for (int j = 0; j < 16; j++) {
      int rbase = j * 8;
      int row = rbase + (lane >> 3);
      int gseg = (lane & 7) ^ (row & 7);
      gl_lds16(Vg + (size_t)row * T_ + kb + gseg * 8, &Vs[rbase * 64]);
    }
    WAIT_VM16();  // K done (16 V-glds still in flight behind S-phase)

    // S^T[kv][q]: A=K-frag, B=qf. 2 t2 x 8 kf MFMA.
    floatx16 sacc[2];
#pragma unroll
    for (int t2 = 0; t2 < 2; t2++)
#pragma unroll
      for (int r = 0; r < 16; r++) sacc[t2][r] = 0.f;
#pragma unroll
    for (int kf = 0; kf < 8; kf++) {
#pragma unroll
      for (int t2 = 0; t2 < 2; t2++) {
        short8 kfr = *(const short8*)&Ks[(t2 * 32 + l32) * 128 +
                                         ((kf * 2 + hi) ^ (lane & 15)) * 8];
        sacc[t2] = __builtin_amdgcn_mfma_f32_32x32x16_bf16(kfr, qf[kf], sacc[t2], 0, 0, 0);
      }
    }

    // causal mask: kv = kb + t2*32 + (r&3)+8*(r>>2)+4*hi; q = qg
    if (kb + 63 > qb) {
#pragma unroll
      for (int t2 = 0; t2 < 2; t2++)
#pragma unroll
        for (int r = 0; r < 16; r++) {
          int kv = kb + t2 * 32 + (r & 3) + 8 * (r >> 2) + 4 * hi;
          if (kv > qg) sacc[t2][r] = -1e30f;
        }
    }

    // online softmax: 32 in-lane values + 1 shfl_xor(32)
    float mx = -1e30f;
#pragma unroll
    for (int t2 = 0; t2 < 2; t2++)
#pragma unroll
      for (int r = 0; r < 16; r++) mx = fmaxf(mx, sacc[t2][r]);
    mx = fmaxf(mx, __shfl_xor(mx, 32, 64));
    float mnew = fmaxf(mval, mx);
    float alpha = EXP2F(mval - mnew);
    mval = mnew;
    float ps = 0.f;
#pragma unroll
    for (int t2 = 0; t2 < 2; t2++)
#pragma unroll
      for (int r = 0; r < 16; r++) {
        float p = EXP2F(sacc[t2][r] - mnew);
        sacc[t2][r] = p;
        ps += p;
      }
    ps += __shfl_xor(ps, 32, 64);
    lval = lval * alpha + ps;
#pragma unroll
    for (int dt = 0; dt < 4; dt++)
#pragma unroll
      for (int r = 0; r < 16; r++) oacc[dt][r] *= alpha;

    // P -> LDS (C/D -> B-operand layout), per-wave private, DS in-order
#pragma unroll
    for (int t2 = 0; t2 < 2; t2++)
#pragma unroll
      for (int rg = 0; rg < 4; rg++) {
        int kvb = t2 * 32 + 8 * rg + 4 * hi;
        short4v pk;
        pk.x = (short)f2b(sacc[t2][rg * 4 + 0]);
        pk.y = (short)f2b(sacc[t2][rg * 4 + 1]);
        pk.z = (short)f2b(sacc[t2][rg * 4 + 2]);
        pk.w = (short)f2b(sacc[t2][rg * 4 + 3]);
        *(short4v*)&Ps[l32 * PLD2 + kvb] = pk;
      }

    WAIT_VM0();  // V staging done
    // O^T += V^T.P: 4 kf x 4 dt MFMA
#pragma unroll
    for (int kf = 0; kf < 4; kf++) {
      short8 pf = *(const short8*)&Ps[l32 * PLD2 + kf * 16 + hi * 8];
#pragma unroll
      for (int dt = 0; dt < 4; dt++) {
        short8 vf = *(const short8*)&Vs[(dt * 32 + l32) * 64 +
                                        ((kf * 2 + hi) ^ (lane & 7)) * 8];
        oacc[dt] = __builtin_amdgcn_mfma_f32_32x32x16_bf16(vf, pf, oacc[dt], 0, 0, 0);
      }
    }
  }

  // merge: wave1 publishes (m,l,O) via LDS; wave0 combines + stores
  float* Om = (float*)&Buf[1][0];  // overlay wave1's K/V region (16 KB)
  if (wv == 1) {
    if (hi == 0) { Ms[l32] = mval; Ls[l32] = lval; }
#pragma unroll
    for (int dt = 0; dt < 4; dt++)
#pragma unroll
      for (int r = 0; r < 16; r++) {
        int d = dt * 32 + (r & 3) + 8 * (r >> 2) + 4 * hi;
        Om[d * 32 + l32] = oacc[dt][r];
      }
  }
  __syncthreads();
  if (wv == 0) {
    float m1 = Ms[l32], l1 = Ls[l32];
    float mstar = fmaxf(mval, m1);
    float a0 = EXP2F(mval - mstar);
    float a1 = EXP2F(m1 - mstar);
    float linv = 1.f / (lval * a0 + l1 * a1);
    float* Og = Out + ((size_t)batch * T_ + qg) * D_;
#pragma unroll
    for (int dt = 0; dt < 4; dt++)
#pragma unroll
      for (int rg = 0; rg < 4; rg++) {
        int dbase = dt * 32 + 8 * rg + 4 * hi;
        float4 o;
        o.x = (oacc[dt][rg * 4 + 0] * a0 + Om[(dbase + 0) * 32 + l32] * a1) * linv;
        o.y = (oacc[dt][rg * 4 + 1] * a0 + Om[(dbase + 1) * 32 + l32] * a1) * linv;
        o.z = (oacc[dt][rg * 4 + 2] * a0 + Om[(dbase + 2) * 32 + l32] * a1) * linv;
        o.w = (oacc[dt][rg * 4 + 3] * a0 + Om[(dbase + 3) * 32 + l32] * a1) * linv;
        *(float4*)&Og[dbase] = o;
      }
  }
}

// ---------------------------------------------------------------------------
extern "C" void kernel_launch(void* const* d_in, const int* in_sizes, int n_in,
                              void* d_out, int out_size, void* d_ws, size_t ws_size,
                              hipStream_t stream) {
  const float* X  = (const float*)d_in[0];
  const float* Wq = (const float*)d_in[1];
  const float* Wk = (const float*)d_in[2];
  const float* Wv = (const float*)d_in[3];
  float* Out = (float*)d_out;

  char* ws = (char*)d_ws;
  unsigned short* Wt3 = (unsigned short*)(ws);                        // 768 KB
  unsigned short* Qb  = (unsigned short*)(ws + 786432);               // 4 MB
  unsigned short* Kb  = (unsigned short*)(ws + 786432 + 4194304);     // 4 MB
  unsigned short* Vt  = (unsigned short*)(ws + 786432 + 2 * 4194304); // 4 MB

  hipLaunchKernelGGL(wtrans_kernel, dim3(96), dim3(256), 0, stream, Wq, Wk, Wv, Wt3);
  hipLaunchKernelGGL(qkv_kernel, dim3(512), dim3(256), 0, stream, X, Wt3, Qb, Kb, Vt);
  hipLaunchKernelGGL(attn_kernel, dim3(512), dim3(128), 0, stream, Qb, Kb, Vt, Out);
}